// Round 1
// baseline (145.812 us; speedup 1.0000x reference)
//
#include <hip/hip_runtime.h>

#define SOB_H 256
#define SOB_W 256

// One wave (64 lanes x float4) = one full row of 256 pixels.
// Block = 256 threads = 4 waves = 4 consecutive rows of one (b,c) plane.
// Halo columns come from neighbor lanes via shuffles; halo rows are two
// extra aligned float4 loads (served from L1/L2 due to inter-wave reuse).
__global__ __launch_bounds__(256) void sobel_kernel(const float* __restrict__ in,
                                                    float* __restrict__ out) {
    const int lane = threadIdx.x & 63;
    const int wave = threadIdx.x >> 6;
    const int rowgroup = blockIdx.x & 63;   // 64 row-groups of 4 rows
    const int plane = blockIdx.x >> 6;      // B*C = 1024 planes
    const int row = rowgroup * 4 + wave;
    const int col = lane * 4;

    const long long planeOff = (long long)plane * (SOB_H * SOB_W);
    const float* p = in + planeOff + (long long)row * SOB_W + col;

    const float4 zero4 = make_float4(0.f, 0.f, 0.f, 0.f);
    float4 mid = *(const float4*)(p);
    float4 top = (row > 0)         ? *(const float4*)(p - SOB_W) : zero4;
    float4 bot = (row < SOB_H - 1) ? *(const float4*)(p + SOB_W) : zero4;

    // Halo elements from neighboring lanes (wave = 64 lanes on CDNA).
    float tL = __shfl_up(top.w, 1);   if (lane == 0)  tL = 0.f;
    float mL = __shfl_up(mid.w, 1);   if (lane == 0)  mL = 0.f;
    float bL = __shfl_up(bot.w, 1);   if (lane == 0)  bL = 0.f;
    float tR = __shfl_down(top.x, 1); if (lane == 63) tR = 0.f;
    float mR = __shfl_down(mid.x, 1); if (lane == 63) mR = 0.f;
    float bR = __shfl_down(bot.x, 1); if (lane == 63) bR = 0.f;

    // t[c], c in [0,5] maps to input column col-1+c
    const float t[6] = {tL, top.x, top.y, top.z, top.w, tR};
    const float m[6] = {mL, mid.x, mid.y, mid.z, mid.w, mR};
    const float b[6] = {bL, bot.x, bot.y, bot.z, bot.w, bR};

    float4 o;
    float* op = &o.x;
#pragma unroll
    for (int c = 0; c < 4; ++c) {
        // cross-correlation (JAX conv does NOT flip the kernel)
        float gx = (t[c + 2] - t[c]) + 2.f * (m[c + 2] - m[c]) + (b[c + 2] - b[c]);
        float gy = (t[c] + 2.f * t[c + 1] + t[c + 2]) - (b[c] + 2.f * b[c + 1] + b[c + 2]);
        op[c] = fabsf(gx) + fabsf(gy);
    }

    *(float4*)(out + planeOff + (long long)row * SOB_W + col) = o;
}

extern "C" void kernel_launch(void* const* d_in, const int* in_sizes, int n_in,
                              void* d_out, int out_size, void* d_ws, size_t ws_size,
                              hipStream_t stream) {
    const float* x = (const float*)d_in[0];
    float* out = (float*)d_out;
    const int planes = in_sizes[0] / (SOB_H * SOB_W);      // 16*64 = 1024
    const int blocks = planes * (SOB_H / 4);               // 65536
    sobel_kernel<<<blocks, 256, 0, stream>>>(x, out);
}

// Round 3
// 83.992 us; speedup vs baseline: 1.7360x; 1.7360x over previous
//
#include <hip/hip_runtime.h>

#define SOB_H 256
#define SOB_W 256
#define ROWS  8   // output rows per wave

typedef float fx4 __attribute__((ext_vector_type(4)));

// One wave (64 lanes x float4) = one full 256-px row.
// Each wave produces ROWS=8 consecutive output rows via a vertical rolling
// window: 10 aligned float4 loads (8 rows + 2 halo) issued up front, then
// separable Sobel: per loaded row compute h1 = x[c+1]-x[c-1] (gx horizontal)
// and h2 = x[c-1]+2x[c]+x[c+1] (gy horizontal) exactly once (2 shuffles/row),
// combine vertically: gx = h1[t]+2h1[m]+h1[b], gy = h2[t]-h2[b].
__global__ __launch_bounds__(256) void sobel_kernel(const float* __restrict__ in,
                                                    float* __restrict__ out) {
    const int lane = threadIdx.x & 63;
    const int wave = threadIdx.x >> 6;
    const int strip = (blockIdx.x & 7) * 4 + wave;   // 0..31 within plane
    const int plane = blockIdx.x >> 3;               // B*C planes
    const int row0 = strip * ROWS;
    const int col = lane * 4;

    const size_t base = (size_t)plane * (SOB_H * SOB_W) + (size_t)row0 * SOB_W + col;
    const float* p = in + base;

    const fx4 z4 = (fx4)(0.f);

    // Load 10 rows (row0-1 .. row0+8), all independent -> deep VMEM pipeline.
    fx4 r[ROWS + 2];
#pragma unroll
    for (int i = 0; i < ROWS + 2; ++i) {
        const int rr = row0 + i - 1;
        r[i] = (rr >= 0 && rr < SOB_H) ? *(const fx4*)(p + (long)(i - 1) * SOB_W) : z4;
    }

    // Horizontal pass for one loaded row i -> (h1, h2)
    auto hpass = [&](int i, fx4& h1, fx4& h2) {
        float L = __shfl_up(r[i].w, 1);   if (lane == 0)  L = 0.f;
        float R = __shfl_down(r[i].x, 1); if (lane == 63) R = 0.f;
        h1.x = r[i].y - L;
        h1.y = r[i].z - r[i].x;
        h1.z = r[i].w - r[i].y;
        h1.w = R       - r[i].z;
        h2.x = L       + 2.f * r[i].x + r[i].y;
        h2.y = r[i].x  + 2.f * r[i].y + r[i].z;
        h2.z = r[i].y  + 2.f * r[i].z + r[i].w;
        h2.w = r[i].z  + 2.f * r[i].w + R;
    };

    float* q = out + base;

    // Rolling 3-row window of (h1,h2); each h computed exactly once.
    fx4 h1a, h2a, h1b, h2b, h1c, h2c;
    hpass(0, h1a, h2a);
    hpass(1, h1b, h2b);
#pragma unroll
    for (int j = 0; j < ROWS; ++j) {
        hpass(j + 2, h1c, h2c);
        fx4 o;
        o.x = fabsf(h1a.x + 2.f * h1b.x + h1c.x) + fabsf(h2a.x - h2c.x);
        o.y = fabsf(h1a.y + 2.f * h1b.y + h1c.y) + fabsf(h2a.y - h2c.y);
        o.z = fabsf(h1a.z + 2.f * h1b.z + h1c.z) + fabsf(h2a.z - h2c.z);
        o.w = fabsf(h1a.w + 2.f * h1b.w + h1c.w) + fabsf(h2a.w - h2c.w);
        __builtin_nontemporal_store(o, (fx4*)(q + (long)j * SOB_W));
        h1a = h1b; h2a = h2b;
        h1b = h1c; h2b = h2c;
    }
}

extern "C" void kernel_launch(void* const* d_in, const int* in_sizes, int n_in,
                              void* d_out, int out_size, void* d_ws, size_t ws_size,
                              hipStream_t stream) {
    const float* x = (const float*)d_in[0];
    float* out = (float*)d_out;
    const int planes = in_sizes[0] / (SOB_H * SOB_W);        // 16*64 = 1024
    const int blocks = planes * (SOB_H / (ROWS * 4));        // 8 blocks/plane = 8192
    sobel_kernel<<<blocks, 256, 0, stream>>>(x, out);
}